// Round 21
// baseline (325.017 us; speedup 1.0000x reference)
//
#include <hip/hip_runtime.h>

typedef unsigned short u16;
typedef unsigned char u8;
typedef __attribute__((ext_vector_type(8))) short short8;
typedef __attribute__((ext_vector_type(4))) float f32x4;
typedef __attribute__((ext_vector_type(4))) int int4v;

#define Bn 4096
#define Vn 20
#define Dn 768
#define Mn (Bn * Vn)   // 81920 rows
#define Nn (2 * Dn)    // 1536 packed m1/m2 columns
#define NW (Dn * Dn)   // 589824 weights per matrix

#define BM 256
#define BNt 256            // Wt rows per block tile (= 128 output e-columns)
#define NTILES (Nn / BNt)  // 6 N-tiles
#define GRID ((Mn / BM) * NTILES)   // 320 * 6 = 1920, %8 == 0
#define PANEL (256 * Dn)   // bytes per 256-row i8 panel (196608)

typedef __attribute__((address_space(1))) void GV;
typedef __attribute__((address_space(3))) void LV;

__device__ __forceinline__ u16 f2bf(float f) {
  union { float f; unsigned u; } v; v.f = f;
  unsigned r = v.u + 0x7FFFu + ((v.u >> 16) & 1u);  // round-to-nearest-even
  return (u16)(r >> 16);
}
__device__ __forceinline__ float bf2f(u16 x) {
  union { unsigned u; float f; } v; v.u = ((unsigned)x) << 16; return v.f;
}

// Tiled i8 layout v3 (GLOBAL == LDS, identity copy): a 256-row x 64-byte
// K-tile (16384 B region) stored as [4 hi-planes(4096B)][256 rows][16B]:
//   byte(q, kb) = hi*4096 + q*16 + b,  hi = kb>>4, b = kb&15.
// Fragment (lane lo,hi; row q=R0+lo): ONE ds_read_b128 at hi*4096 + q*16 =
// k-bytes [hi*16,+16) — the 16x16x64-i8 A/B fragment (byte-identical shape
// to the verified bf16 16x16x32 map). 16-lane pass = 256 contiguous B.

// ---------------- kernel 0a/0b: global max|W| reduction ---------------------
__global__ void zero_k(unsigned* wm) { *wm = 0u; }

__global__ __launch_bounds__(256) void wmax_k(const float* __restrict__ W1,
                                              const float* __restrict__ W2,
                                              unsigned* __restrict__ wm) {
  float m = 0.f;
  for (int i = blockIdx.x * 256 + threadIdx.x; i < 2 * NW; i += gridDim.x * 256) {
    float a = fabsf(i < NW ? W1[i] : W2[i - NW]);
    m = fmaxf(m, a);
  }
  #pragma unroll
  for (int off = 32; off; off >>= 1) m = fmaxf(m, __shfl_xor(m, off));
  if ((threadIdx.x & 63) == 0) atomicMax(wm, __float_as_uint(m));
}

// ---- kernel 1: softmax -> i8 (q = round(127*exp)), layout v3, + invs -------
// 512 thr = 32 rows x 16 lanes. Lane g, unit u owns e = g*4 + u*64 (+c):
// kb = g*4+c -> hi = g>>2, b = (g&3)*4+c. LDS image: u*2048 + hi*512 + r*16
// + (g&3)*4 (+c). Copy-out per 512B chunk -> global tile*16384 + hi*4096 +
// q0*16 (identical structure to the verified R20 copy).
__global__ __launch_bounds__(512) void softmax_k(const float* __restrict__ vf,
                                                 u8* __restrict__ X8,
                                                 float* __restrict__ invs) {
  __shared__ __align__(16) u8 lds[24576];
  const int t = threadIdx.x;
  const int r = t >> 4;                         // row-in-block 0..31
  const int g = t & 15;                         // lane-in-group
  const size_t row = (size_t)blockIdx.x * 32 + r;
  const float* src = vf + row * Dn + g * 4;
  float4 v[12];
  #pragma unroll
  for (int u = 0; u < 12; ++u) v[u] = *(const float4*)(src + u * 64);
  float mx = -1e30f;
  #pragma unroll
  for (int u = 0; u < 12; ++u)
    mx = fmaxf(mx, fmaxf(fmaxf(v[u].x, v[u].y), fmaxf(v[u].z, v[u].w)));
  #pragma unroll
  for (int off = 1; off < 16; off <<= 1) mx = fmaxf(mx, __shfl_xor(mx, off));
  float s = 0.f;
  #pragma unroll
  for (int u = 0; u < 12; ++u) {
    v[u].x = __expf(v[u].x - mx); v[u].y = __expf(v[u].y - mx);
    v[u].z = __expf(v[u].z - mx); v[u].w = __expf(v[u].w - mx);
    s += (v[u].x + v[u].y) + (v[u].z + v[u].w);
  }
  #pragma unroll
  for (int off = 1; off < 16; off <<= 1) s += __shfl_xor(s, off);
  if (g == 0) invs[row] = 1.0f / s;
  const int base = (g >> 2) * 512 + r * 16 + (g & 3) * 4;
  #pragma unroll
  for (int u = 0; u < 12; ++u) {
    unsigned i0 = (unsigned)__float2int_rn(v[u].x * 127.f);
    unsigned i1 = (unsigned)__float2int_rn(v[u].y * 127.f);
    unsigned i2 = (unsigned)__float2int_rn(v[u].z * 127.f);
    unsigned i3 = (unsigned)__float2int_rn(v[u].w * 127.f);
    *(unsigned*)(lds + u * 2048 + base) = i0 | (i1 << 8) | (i2 << 16) | (i3 << 24);
  }
  __syncthreads();
  u8* dst = X8 + (size_t)(blockIdx.x >> 3) * PANEL + (blockIdx.x & 7) * 512;
  #pragma unroll
  for (int rd = 0; rd < 3; ++rd) {
    const int o = (rd * 512 + t) * 16;
    const int chunk = o >> 9;
    *(uint4*)(dst + (chunk >> 2) * 16384 + (chunk & 3) * 4096 + (o & 511)) =
        *(const uint4*)(lds + o);
  }
}

// ---- kernel 2: pack W1/W2 block-of-32 interleaved, i8 (127/wmax), v3 -------
__global__ __launch_bounds__(256) void build_wt_k(const float* __restrict__ W1,
                                                  const float* __restrict__ W2,
                                                  u8* __restrict__ Wt8,
                                                  const unsigned* __restrict__ wm) {
  int idx = blockIdx.x * 256 + threadIdx.x;        // over 768 * 192
  if (idx >= Dn * (Dn / 4)) return;
  const float aw = 127.0f / __uint_as_float(*wm);
  int j = idx / (Dn / 4), d4 = (idx - j * (Dn / 4)) * 4;
  int b = j >> 5, c = j & 31;
  float4 a = *(const float4*)(W1 + (size_t)j * Dn + d4);
  float4 e = *(const float4*)(W2 + (size_t)j * Dn + d4);
  #define Q8(x) ((unsigned)(min(127, max(-127, __float2int_rn((x) * aw))) & 255))
  unsigned p1 = Q8(a.x) | (Q8(a.y) << 8) | (Q8(a.z) << 16) | (Q8(a.w) << 24);
  unsigned p2 = Q8(e.x) | (Q8(e.y) << 8) | (Q8(e.z) << 16) | (Q8(e.w) << 24);
  #undef Q8
  const size_t off = (size_t)(d4 >> 6) * 16384 + ((d4 >> 4) & 3) * 4096 + (d4 & 15);
  const int j1 = b * 64 + c, j2 = b * 64 + 32 + c;
  *(unsigned*)(Wt8 + (size_t)(j1 >> 8) * PANEL + off + (j1 & 255) * 16) = p1;
  *(unsigned*)(Wt8 + (size_t)(j2 >> 8) * PANEL + off + (j2 & 255) * 16) = p2;
}

// -------- kernel 3: i8 GEMM, 1-phase/K-tile 3-slot ring + fused conv --------
// Same schedule/ledger as verified R20; MFMA halves to 32/tile via
// mfma_i32_16x16x64_i8 (2x rate, exact i32 accum). Epilogue scale:
// m = acc * invs[row] * wmax / (127*127).
__global__ __launch_bounds__(512, 2) void gemm_fuse_k(
    const u8* __restrict__ X8, const u8* __restrict__ Wt8,
    const float* __restrict__ b1, const float* __restrict__ b2,
    const float* __restrict__ text, float* __restrict__ out,
    u16* __restrict__ seam, const float* __restrict__ invs,
    const unsigned* __restrict__ wmp,
    const float* __restrict__ cw1, const float* __restrict__ cb1,
    const float* __restrict__ cw2, const float* __restrict__ cb2) {
  __shared__ __align__(16) u16 smem[65536];   // 128 KiB (K-loop uses 96 KiB)
  u8* smem8 = (u8*)smem;

  const int h = blockIdx.x;                      // GRID = 1920 blocks, %8==0
  const int lin = (h & 7) * (GRID / 8) + (h >> 3);
  const int by = lin / NTILES, bx = lin - by * NTILES;
  const int brow = by * BM;

  const int t = threadIdx.x, w = t >> 6, l = t & 63;
  const int lo = l & 15, hi = l >> 4;
  const int wrr = w >> 2, wcc = w & 3;

  int offA[8], offB[4];
  #pragma unroll
  for (int m = 0; m < 8; ++m)
    offA[m] = hi * 4096 + (wrr * 128 + m * 16 + lo) * 16;
  #pragma unroll
  for (int n = 0; n < 4; ++n)
    offB[n] = 16384 + hi * 4096 + (wcc * 64 + n * 16 + lo) * 16;

  // staging: tiled global region is byte-identical to the LDS region
  const u8* gAp = X8 + (size_t)by * PANEL + t * 16;
  const u8* gBp = Wt8 + (size_t)bx * PANEL + t * 16;

#define STG_A(SB, T) do {                                                      \
    __builtin_amdgcn_global_load_lds((GV*)(gAp + (size_t)(T) * 16384),         \
        (LV*)(smem8 + (SB) + w * 1024), 16, 0, 0);                             \
    __builtin_amdgcn_global_load_lds((GV*)(gAp + (size_t)(T) * 16384 + 8192),  \
        (LV*)(smem8 + (SB) + 8192 + w * 1024), 16, 0, 0); } while (0)
#define STG_B(SB, T) do {                                                      \
    __builtin_amdgcn_global_load_lds((GV*)(gBp + (size_t)(T) * 16384),         \
        (LV*)(smem8 + (SB) + 16384 + w * 1024), 16, 0, 0);                     \
    __builtin_amdgcn_global_load_lds((GV*)(gBp + (size_t)(T) * 16384 + 8192),  \
        (LV*)(smem8 + (SB) + 24576 + w * 1024), 16, 0, 0); } while (0)

  // prologue: tiles 0,1 (8 loads); vmcnt(4) -> T0 resident
  STG_A(0, 0);     STG_B(0, 0);
  STG_A(32768, 1); STG_B(32768, 1);
  asm volatile("s_waitcnt vmcnt(4)" ::: "memory");
  __builtin_amdgcn_s_barrier();

  int4v acc[8][4] = {};
  int4v af[8], bb[4];

  #pragma unroll
  for (int T = 0; T < 12; ++T) {
    const int cs = (T % 3) * 32768;          // compute slot base
    const int ss = ((T + 2) % 3) * 32768;    // stage slot base

    #pragma unroll
    for (int m = 0; m < 8; ++m)
      af[m] = *(const int4v*)(smem8 + cs + offA[m]);
    #pragma unroll
    for (int n = 0; n < 4; ++n)
      bb[n] = *(const int4v*)(smem8 + cs + offB[n]);
    if (T <= 9) { STG_A(ss, T + 2); STG_B(ss, T + 2); }
    __builtin_amdgcn_s_barrier();
    asm volatile("s_waitcnt lgkmcnt(0)" ::: "memory");
    __builtin_amdgcn_sched_barrier(0);
    __builtin_amdgcn_s_setprio(1);
    #pragma unroll
    for (int m = 0; m < 8; ++m)
      #pragma unroll
      for (int n = 0; n < 4; ++n)
        acc[m][n] = __builtin_amdgcn_mfma_i32_16x16x64_i8(af[m], bb[n], acc[m][n], 0, 0, 0);
    __builtin_amdgcn_s_setprio(0);
    if (T <= 9)       asm volatile("s_waitcnt vmcnt(4)" ::: "memory");
    else if (T == 10) asm volatile("s_waitcnt vmcnt(0)" ::: "memory");
    __builtin_amdgcn_s_barrier();
  }
#undef STG_A
#undef STG_B

  // ======================= fused-conv epilogue ==============================
  const float w10 = cw1[0], w11 = cw1[1], w12 = cw1[2], c1b = cb1[0];
  const float w20 = cw2[0], w21 = cw2[1], w22 = cw2[2], c2b = cb2[0];
  const float wsc = __uint_as_float(*wmp) * (1.0f / 16129.0f);

  u16* fsm = smem;           // fused [c][r]: idx = c*256 + (r ^ ((c&31)<<3))
  u16* tsm = smem + 32768;   // tmp, same layout

  // ---- E1: fused -> LDS bf16 (+ seam store for cols 0-3,124-127) ----
  #pragma unroll
  for (int n = 0; n < 2; ++n) {
    const int cl = wcc * 32 + n * 16 + lo;       // local col 0..127
    const int e  = bx * 128 + cl;
    const float B1 = b1[e], B2 = b2[e];
    #pragma unroll
    for (int m = 0; m < 8; ++m) {
      const int rl = wrr * 128 + m * 16 + hi * 4;
      uint2 pk;
      u16* pku = (u16*)&pk;
      #pragma unroll
      for (int r = 0; r < 4; ++r) {
        const int gr = brow + rl + r;
        const float scr = invs[gr] * wsc;
        const float v1 = (float)acc[m][n][r] * scr + B1;
        const float v2 = (float)acc[m][n + 2][r] * scr + B2;
        const float tf = text[(size_t)(gr / Vn) * Dn + e];
        pku[r] = f2bf(fmaxf(tf * v1 + v2, 0.0f));
      }
      *(uint2*)(fsm + cl * 256 + (rl ^ ((cl & 31) << 3))) = pk;
      const int sidx = (cl < 4) ? cl : ((cl >= 124) ? cl - 120 : -1);
      if (sidx >= 0)
        *(uint2*)(seam + ((size_t)(by * 6 + bx) * 8 + sidx) * 256 + rl) = pk;
    }
  }
  __syncthreads();

  // ---- E2: tmp = relu(conv1(fused)), per-thread col; own col kept in regs --
  const int cl = t & 127, rb = t >> 7;
  const int cL = cl ? cl - 1 : 0, cR = (cl < 127) ? cl + 1 : 127;
  short8 tC[8];
  #pragma unroll
  for (int j = 0; j < 8; ++j) {
    const int R = rb * 64 + j * 8;
    short8 sL = *(const short8*)(fsm + cL * 256 + (R ^ ((cL & 31) << 3)));
    short8 sC = *(const short8*)(fsm + cl * 256 + (R ^ ((cl & 31) << 3)));
    short8 sR = *(const short8*)(fsm + cR * 256 + (R ^ ((cR & 31) << 3)));
    short8 o;
    #pragma unroll
    for (int k = 0; k < 8; ++k) {
      float a = bf2f((u16)sL[k]), b = bf2f((u16)sC[k]), c = bf2f((u16)sR[k]);
      float v = fmaxf(fmaf(w10, a, fmaf(w11, b, fmaf(w12, c, c1b))), 0.0f);
      o[k] = (short)f2bf(v);
    }
    *(short8*)(tsm + cl * 256 + (R ^ ((cl & 31) << 3))) = o;
    tC[j] = o;
  }
  __syncthreads();

  // ---- E3: out = conv2(tmp), store interior cols 2..125 ----
  const bool wr_ok = (cl >= 2 && cl <= 125);
  #pragma unroll
  for (int j = 0; j < 8; ++j) {
    const int R = rb * 64 + j * 8;
    short8 tL = *(const short8*)(tsm + cL * 256 + (R ^ ((cL & 31) << 3)));
    short8 tR = *(const short8*)(tsm + cR * 256 + (R ^ ((cR & 31) << 3)));
    #pragma unroll
    for (int k = 0; k < 8; ++k) {
      float v = fmaf(w20, bf2f((u16)tL[k]),
                fmaf(w21, bf2f((u16)tC[j][k]),
                fmaf(w22, bf2f((u16)tR[k]), c2b)));
      if (wr_ok)
        out[(size_t)(brow + R + k) * Dn + bx * 128 + cl] = v;
    }
  }
}

// ------- kernel 4: seam cleanup — out cols {E0,E0+1,E0+126,E0+127} ---------
__global__ __launch_bounds__(256) void seam_k(const u16* __restrict__ seam,
                                              float* __restrict__ out,
                                              const float* __restrict__ cw1,
                                              const float* __restrict__ cb1,
                                              const float* __restrict__ cw2,
                                              const float* __restrict__ cb2) {
  const int bid = blockIdx.x;          // by*6+bx
  const int by = bid / 6, bx = bid - by * 6;
  const int r = threadIdx.x;
  const float w10 = cw1[0], w11 = cw1[1], w12 = cw1[2], c1b = cb1[0];
  const float w20 = cw2[0], w21 = cw2[1], w22 = cw2[2], c2b = cb2[0];
  #define SM(B, I) bf2f(seam[((size_t)(B) * 8 + (I)) * 256 + r])
  float fm2 = 0.f, fm1 = 0.f, fR0 = 0.f, fR1 = 0.f;
  if (bx > 0) { fm2 = SM(bid - 1, 6); fm1 = SM(bid - 1, 7); }
  if (bx < 5) { fR0 = SM(bid + 1, 0); fR1 = SM(bid + 1, 1); }
  const float f0 = SM(bid, 0), f1 = SM(bid, 1), f2 = SM(bid, 2), f3 = SM(bid, 3);
  const float f124 = SM(bid, 4), f125 = SM(bid, 5), f126 = SM(bid, 6), f127 = SM(bid, 7);
  #undef SM
  #define C1(a, b, c) fmaxf(fmaf(w10, (a), fmaf(w11, (b), fmaf(w12, (c), c1b))), 0.0f)
  const float tm1  = (bx > 0) ? C1(fm2, fm1, f0) : 0.0f;   // tmp(-1)=0 at edge
  const float t0   = C1(fm1, f0, f1);
  const float t1   = C1(f0, f1, f2);
  const float t2   = C1(f1, f2, f3);
  const float t125 = C1(f124, f125, f126);
  const float t126 = C1(f125, f126, f127);
  const float t127 = C1(f126, f127, fR0);
  const float t128 = (bx < 5) ? C1(f127, fR0, fR1) : 0.0f;  // tmp(768)=0 at edge
  #undef C1
  const size_t go = (size_t)(by * 256 + r) * Dn + bx * 128;
  out[go + 0]   = fmaf(w20, tm1,  fmaf(w21, t0,   fmaf(w22, t1,   c2b)));
  out[go + 1]   = fmaf(w20, t0,   fmaf(w21, t1,   fmaf(w22, t2,   c2b)));
  out[go + 126] = fmaf(w20, t125, fmaf(w21, t126, fmaf(w22, t127, c2b)));
  out[go + 127] = fmaf(w20, t126, fmaf(w21, t127, fmaf(w22, t128, c2b)));
}

extern "C" void kernel_launch(void* const* d_in, const int* in_sizes, int n_in,
                              void* d_out, int out_size, void* d_ws, size_t ws_size,
                              hipStream_t stream) {
  const float* text = (const float*)d_in[0];
  const float* vf   = (const float*)d_in[1];
  const float* W1   = (const float*)d_in[2];
  const float* b1   = (const float*)d_in[3];
  const float* W2   = (const float*)d_in[4];
  const float* b2   = (const float*)d_in[5];
  const float* cw1  = (const float*)d_in[6];
  const float* cb1  = (const float*)d_in[7];
  const float* cw2  = (const float*)d_in[8];
  const float* cb2  = (const float*)d_in[9];
  float* out = (float*)d_out;

  u8*  X8   = (u8*)d_ws;                                   // [320 panels] tiled i8 v3
  u8*  Wt8  = X8 + (size_t)Mn * Dn;                        // [6 panels] tiled i8 v3
  u16* seam = (u16*)(Wt8 + (size_t)Nn * Dn);               // [1920][8][256] bf16
  float* invs = (float*)(seam + (size_t)GRID * 8 * 256);   // [81920] per-row 1/s
  unsigned* wm = (unsigned*)(invs + Mn);                   // global max|W|

  zero_k<<<1, 1, 0, stream>>>(wm);
  wmax_k<<<512, 256, 0, stream>>>(W1, W2, wm);
  softmax_k<<<Mn / 32, 512, 0, stream>>>(vf, X8, invs);
  build_wt_k<<<(Dn * (Dn / 4) + 255) / 256, 256, 0, stream>>>(W1, W2, Wt8, wm);
  gemm_fuse_k<<<GRID, 512, 0, stream>>>(X8, Wt8, b1, b2, text, out, seam,
                                        invs, wm, cw1, cb1, cw2, cb2);
  seam_k<<<GRID, 256, 0, stream>>>(seam, out, cw1, cb1, cw2, cb2);
}

// Round 22
// 304.622 us; speedup vs baseline: 1.0670x; 1.0670x over previous
//
#include <hip/hip_runtime.h>

typedef unsigned short u16;
typedef unsigned char u8;
typedef __attribute__((ext_vector_type(8))) short short8;
typedef __attribute__((ext_vector_type(4))) float f32x4;
typedef __attribute__((ext_vector_type(4))) int int4v;

#define Bn 4096
#define Vn 20
#define Dn 768
#define Mn (Bn * Vn)   // 81920 rows
#define Nn (2 * Dn)    // 1536 packed m1/m2 columns
#define NW (Dn * Dn)   // 589824 weights per matrix

#define BM 256
#define BNt 256            // Wt rows per block tile (= 128 output e-columns)
#define NTILES (Nn / BNt)  // 6 N-tiles
#define GRID ((Mn / BM) * NTILES)   // 320 * 6 = 1920, %8 == 0
#define PANEL (256 * Dn)   // bytes per 256-row i8 panel (196608)

typedef __attribute__((address_space(1))) void GV;
typedef __attribute__((address_space(3))) void LV;

__device__ __forceinline__ u16 f2bf(float f) {
  union { float f; unsigned u; } v; v.f = f;
  unsigned r = v.u + 0x7FFFu + ((v.u >> 16) & 1u);  // round-to-nearest-even
  return (u16)(r >> 16);
}
__device__ __forceinline__ float bf2f(u16 x) {
  union { unsigned u; float f; } v; v.u = ((unsigned)x) << 16; return v.f;
}

// Tiled i8 layout v3 (GLOBAL == LDS, identity copy): a 256-row x 64-byte
// K-tile (16384 B region) stored as [4 hi-planes(4096B)][256 rows][16B]:
//   byte(q, kb) = hi*4096 + q*16 + b,  hi = kb>>4, b = kb&15.
// Fragment (lane lo,hi; row q=R0+lo): ONE ds_read_b128 at hi*4096 + q*16 =
// k-bytes [hi*16,+16) — the 16x16x64-i8 A/B fragment. 16-lane pass = 256
// contiguous bytes -> conflict-free.

// ---------------- kernel 0a/0b: global max|W| reduction ---------------------
__global__ void zero_k(unsigned* wm) { *wm = 0u; }

// 64 blocks x 256 thr, float4 loads, wave reduce -> LDS reduce -> ONE atomic
// per block (64 total).  R21's version issued 2048 same-address device-scope
// atomics (Guideline 12 violation) costing ~35us.
__global__ __launch_bounds__(256) void wmax_k(const float* __restrict__ W1,
                                              const float* __restrict__ W2,
                                              unsigned* __restrict__ wm) {
  __shared__ float red[4];
  const int stride = 64 * 256;                 // threads total
  float m = 0.f;
  for (int i = blockIdx.x * 256 + threadIdx.x; i < NW / 4; i += stride) {
    float4 a = ((const float4*)W1)[i];
    float4 b = ((const float4*)W2)[i];
    m = fmaxf(m, fmaxf(fmaxf(fabsf(a.x), fabsf(a.y)), fmaxf(fabsf(a.z), fabsf(a.w))));
    m = fmaxf(m, fmaxf(fmaxf(fabsf(b.x), fabsf(b.y)), fmaxf(fabsf(b.z), fabsf(b.w))));
  }
  #pragma unroll
  for (int off = 32; off; off >>= 1) m = fmaxf(m, __shfl_xor(m, off));
  if ((threadIdx.x & 63) == 0) red[threadIdx.x >> 6] = m;
  __syncthreads();
  if (threadIdx.x == 0) {
    m = fmaxf(fmaxf(red[0], red[1]), fmaxf(red[2], red[3]));
    atomicMax(wm, __float_as_uint(m));
  }
}

// ---- kernel 1: softmax -> i8 (q = round(127*exp)), layout v3, + invs -------
__global__ __launch_bounds__(512) void softmax_k(const float* __restrict__ vf,
                                                 u8* __restrict__ X8,
                                                 float* __restrict__ invs) {
  __shared__ __align__(16) u8 lds[24576];
  const int t = threadIdx.x;
  const int r = t >> 4;                         // row-in-block 0..31
  const int g = t & 15;                         // lane-in-group
  const size_t row = (size_t)blockIdx.x * 32 + r;
  const float* src = vf + row * Dn + g * 4;
  float4 v[12];
  #pragma unroll
  for (int u = 0; u < 12; ++u) v[u] = *(const float4*)(src + u * 64);
  float mx = -1e30f;
  #pragma unroll
  for (int u = 0; u < 12; ++u)
    mx = fmaxf(mx, fmaxf(fmaxf(v[u].x, v[u].y), fmaxf(v[u].z, v[u].w)));
  #pragma unroll
  for (int off = 1; off < 16; off <<= 1) mx = fmaxf(mx, __shfl_xor(mx, off));
  float s = 0.f;
  #pragma unroll
  for (int u = 0; u < 12; ++u) {
    v[u].x = __expf(v[u].x - mx); v[u].y = __expf(v[u].y - mx);
    v[u].z = __expf(v[u].z - mx); v[u].w = __expf(v[u].w - mx);
    s += (v[u].x + v[u].y) + (v[u].z + v[u].w);
  }
  #pragma unroll
  for (int off = 1; off < 16; off <<= 1) s += __shfl_xor(s, off);
  if (g == 0) invs[row] = 1.0f / s;
  const int base = (g >> 2) * 512 + r * 16 + (g & 3) * 4;
  #pragma unroll
  for (int u = 0; u < 12; ++u) {
    unsigned i0 = (unsigned)__float2int_rn(v[u].x * 127.f);
    unsigned i1 = (unsigned)__float2int_rn(v[u].y * 127.f);
    unsigned i2 = (unsigned)__float2int_rn(v[u].z * 127.f);
    unsigned i3 = (unsigned)__float2int_rn(v[u].w * 127.f);
    *(unsigned*)(lds + u * 2048 + base) = i0 | (i1 << 8) | (i2 << 16) | (i3 << 24);
  }
  __syncthreads();
  u8* dst = X8 + (size_t)(blockIdx.x >> 3) * PANEL + (blockIdx.x & 7) * 512;
  #pragma unroll
  for (int rd = 0; rd < 3; ++rd) {
    const int o = (rd * 512 + t) * 16;
    const int chunk = o >> 9;
    *(uint4*)(dst + (chunk >> 2) * 16384 + (chunk & 3) * 4096 + (o & 511)) =
        *(const uint4*)(lds + o);
  }
}

// ---- kernel 2: pack W1/W2 block-of-32 interleaved, i8 (127/wmax), v3 -------
__global__ __launch_bounds__(256) void build_wt_k(const float* __restrict__ W1,
                                                  const float* __restrict__ W2,
                                                  u8* __restrict__ Wt8,
                                                  const unsigned* __restrict__ wm) {
  int idx = blockIdx.x * 256 + threadIdx.x;        // over 768 * 192
  if (idx >= Dn * (Dn / 4)) return;
  const float aw = 127.0f / __uint_as_float(*wm);
  int j = idx / (Dn / 4), d4 = (idx - j * (Dn / 4)) * 4;
  int b = j >> 5, c = j & 31;
  float4 a = *(const float4*)(W1 + (size_t)j * Dn + d4);
  float4 e = *(const float4*)(W2 + (size_t)j * Dn + d4);
  #define Q8(x) ((unsigned)(min(127, max(-127, __float2int_rn((x) * aw))) & 255))
  unsigned p1 = Q8(a.x) | (Q8(a.y) << 8) | (Q8(a.z) << 16) | (Q8(a.w) << 24);
  unsigned p2 = Q8(e.x) | (Q8(e.y) << 8) | (Q8(e.z) << 16) | (Q8(e.w) << 24);
  #undef Q8
  const size_t off = (size_t)(d4 >> 6) * 16384 + ((d4 >> 4) & 3) * 4096 + (d4 & 15);
  const int j1 = b * 64 + c, j2 = b * 64 + 32 + c;
  *(unsigned*)(Wt8 + (size_t)(j1 >> 8) * PANEL + off + (j1 & 255) * 16) = p1;
  *(unsigned*)(Wt8 + (size_t)(j2 >> 8) * PANEL + off + (j2 & 255) * 16) = p2;
}

// -------- kernel 3: i8 GEMM, 1-phase/K-tile 3-slot ring + fused conv --------
// Identical to the verified R21 kernel (gemm ~195us).
__global__ __launch_bounds__(512, 2) void gemm_fuse_k(
    const u8* __restrict__ X8, const u8* __restrict__ Wt8,
    const float* __restrict__ b1, const float* __restrict__ b2,
    const float* __restrict__ text, float* __restrict__ out,
    u16* __restrict__ seam, const float* __restrict__ invs,
    const unsigned* __restrict__ wmp,
    const float* __restrict__ cw1, const float* __restrict__ cb1,
    const float* __restrict__ cw2, const float* __restrict__ cb2) {
  __shared__ __align__(16) u16 smem[65536];   // 128 KiB (K-loop uses 96 KiB)
  u8* smem8 = (u8*)smem;

  const int h = blockIdx.x;                      // GRID = 1920 blocks, %8==0
  const int lin = (h & 7) * (GRID / 8) + (h >> 3);
  const int by = lin / NTILES, bx = lin - by * NTILES;
  const int brow = by * BM;

  const int t = threadIdx.x, w = t >> 6, l = t & 63;
  const int lo = l & 15, hi = l >> 4;
  const int wrr = w >> 2, wcc = w & 3;

  int offA[8], offB[4];
  #pragma unroll
  for (int m = 0; m < 8; ++m)
    offA[m] = hi * 4096 + (wrr * 128 + m * 16 + lo) * 16;
  #pragma unroll
  for (int n = 0; n < 4; ++n)
    offB[n] = 16384 + hi * 4096 + (wcc * 64 + n * 16 + lo) * 16;

  // staging: tiled global region is byte-identical to the LDS region
  const u8* gAp = X8 + (size_t)by * PANEL + t * 16;
  const u8* gBp = Wt8 + (size_t)bx * PANEL + t * 16;

#define STG_A(SB, T) do {                                                      \
    __builtin_amdgcn_global_load_lds((GV*)(gAp + (size_t)(T) * 16384),         \
        (LV*)(smem8 + (SB) + w * 1024), 16, 0, 0);                             \
    __builtin_amdgcn_global_load_lds((GV*)(gAp + (size_t)(T) * 16384 + 8192),  \
        (LV*)(smem8 + (SB) + 8192 + w * 1024), 16, 0, 0); } while (0)
#define STG_B(SB, T) do {                                                      \
    __builtin_amdgcn_global_load_lds((GV*)(gBp + (size_t)(T) * 16384),         \
        (LV*)(smem8 + (SB) + 16384 + w * 1024), 16, 0, 0);                     \
    __builtin_amdgcn_global_load_lds((GV*)(gBp + (size_t)(T) * 16384 + 8192),  \
        (LV*)(smem8 + (SB) + 24576 + w * 1024), 16, 0, 0); } while (0)

  // prologue: tiles 0,1 (8 loads); vmcnt(4) -> T0 resident
  STG_A(0, 0);     STG_B(0, 0);
  STG_A(32768, 1); STG_B(32768, 1);
  asm volatile("s_waitcnt vmcnt(4)" ::: "memory");
  __builtin_amdgcn_s_barrier();

  int4v acc[8][4] = {};
  int4v af[8], bb[4];

  #pragma unroll
  for (int T = 0; T < 12; ++T) {
    const int cs = (T % 3) * 32768;          // compute slot base
    const int ss = ((T + 2) % 3) * 32768;    // stage slot base

    #pragma unroll
    for (int m = 0; m < 8; ++m)
      af[m] = *(const int4v*)(smem8 + cs + offA[m]);
    #pragma unroll
    for (int n = 0; n < 4; ++n)
      bb[n] = *(const int4v*)(smem8 + cs + offB[n]);
    if (T <= 9) { STG_A(ss, T + 2); STG_B(ss, T + 2); }
    __builtin_amdgcn_s_barrier();
    asm volatile("s_waitcnt lgkmcnt(0)" ::: "memory");
    __builtin_amdgcn_sched_barrier(0);
    __builtin_amdgcn_s_setprio(1);
    #pragma unroll
    for (int m = 0; m < 8; ++m)
      #pragma unroll
      for (int n = 0; n < 4; ++n)
        acc[m][n] = __builtin_amdgcn_mfma_i32_16x16x64_i8(af[m], bb[n], acc[m][n], 0, 0, 0);
    __builtin_amdgcn_s_setprio(0);
    if (T <= 9)       asm volatile("s_waitcnt vmcnt(4)" ::: "memory");
    else if (T == 10) asm volatile("s_waitcnt vmcnt(0)" ::: "memory");
    __builtin_amdgcn_s_barrier();
  }
#undef STG_A
#undef STG_B

  // ======================= fused-conv epilogue ==============================
  const float w10 = cw1[0], w11 = cw1[1], w12 = cw1[2], c1b = cb1[0];
  const float w20 = cw2[0], w21 = cw2[1], w22 = cw2[2], c2b = cb2[0];
  const float wsc = __uint_as_float(*wmp) * (1.0f / 16129.0f);

  u16* fsm = smem;           // fused [c][r]: idx = c*256 + (r ^ ((c&31)<<3))
  u16* tsm = smem + 32768;   // tmp, same layout

  // ---- E1: fused -> LDS bf16 (+ seam store for cols 0-3,124-127) ----
  #pragma unroll
  for (int n = 0; n < 2; ++n) {
    const int cl = wcc * 32 + n * 16 + lo;       // local col 0..127
    const int e  = bx * 128 + cl;
    const float B1 = b1[e], B2 = b2[e];
    #pragma unroll
    for (int m = 0; m < 8; ++m) {
      const int rl = wrr * 128 + m * 16 + hi * 4;
      uint2 pk;
      u16* pku = (u16*)&pk;
      #pragma unroll
      for (int r = 0; r < 4; ++r) {
        const int gr = brow + rl + r;
        const float scr = invs[gr] * wsc;
        const float v1 = (float)acc[m][n][r] * scr + B1;
        const float v2 = (float)acc[m][n + 2][r] * scr + B2;
        const float tf = text[(size_t)(gr / Vn) * Dn + e];
        pku[r] = f2bf(fmaxf(tf * v1 + v2, 0.0f));
      }
      *(uint2*)(fsm + cl * 256 + (rl ^ ((cl & 31) << 3))) = pk;
      const int sidx = (cl < 4) ? cl : ((cl >= 124) ? cl - 120 : -1);
      if (sidx >= 0)
        *(uint2*)(seam + ((size_t)(by * 6 + bx) * 8 + sidx) * 256 + rl) = pk;
    }
  }
  __syncthreads();

  // ---- E2: tmp = relu(conv1(fused)), per-thread col; own col kept in regs --
  const int cl = t & 127, rb = t >> 7;
  const int cL = cl ? cl - 1 : 0, cR = (cl < 127) ? cl + 1 : 127;
  short8 tC[8];
  #pragma unroll
  for (int j = 0; j < 8; ++j) {
    const int R = rb * 64 + j * 8;
    short8 sL = *(const short8*)(fsm + cL * 256 + (R ^ ((cL & 31) << 3)));
    short8 sC = *(const short8*)(fsm + cl * 256 + (R ^ ((cl & 31) << 3)));
    short8 sR = *(const short8*)(fsm + cR * 256 + (R ^ ((cR & 31) << 3)));
    short8 o;
    #pragma unroll
    for (int k = 0; k < 8; ++k) {
      float a = bf2f((u16)sL[k]), b = bf2f((u16)sC[k]), c = bf2f((u16)sR[k]);
      float v = fmaxf(fmaf(w10, a, fmaf(w11, b, fmaf(w12, c, c1b))), 0.0f);
      o[k] = (short)f2bf(v);
    }
    *(short8*)(tsm + cl * 256 + (R ^ ((cl & 31) << 3))) = o;
    tC[j] = o;
  }
  __syncthreads();

  // ---- E3: out = conv2(tmp), store interior cols 2..125 ----
  const bool wr_ok = (cl >= 2 && cl <= 125);
  #pragma unroll
  for (int j = 0; j < 8; ++j) {
    const int R = rb * 64 + j * 8;
    short8 tL = *(const short8*)(tsm + cL * 256 + (R ^ ((cL & 31) << 3)));
    short8 tR = *(const short8*)(tsm + cR * 256 + (R ^ ((cR & 31) << 3)));
    #pragma unroll
    for (int k = 0; k < 8; ++k) {
      float v = fmaf(w20, bf2f((u16)tL[k]),
                fmaf(w21, bf2f((u16)tC[j][k]),
                fmaf(w22, bf2f((u16)tR[k]), c2b)));
      if (wr_ok)
        out[(size_t)(brow + R + k) * Dn + bx * 128 + cl] = v;
    }
  }
}

// ------- kernel 4: seam cleanup — out cols {E0,E0+1,E0+126,E0+127} ---------
__global__ __launch_bounds__(256) void seam_k(const u16* __restrict__ seam,
                                              float* __restrict__ out,
                                              const float* __restrict__ cw1,
                                              const float* __restrict__ cb1,
                                              const float* __restrict__ cw2,
                                              const float* __restrict__ cb2) {
  const int bid = blockIdx.x;          // by*6+bx
  const int by = bid / 6, bx = bid - by * 6;
  const int r = threadIdx.x;
  const float w10 = cw1[0], w11 = cw1[1], w12 = cw1[2], c1b = cb1[0];
  const float w20 = cw2[0], w21 = cw2[1], w22 = cw2[2], c2b = cb2[0];
  #define SM(B, I) bf2f(seam[((size_t)(B) * 8 + (I)) * 256 + r])
  float fm2 = 0.f, fm1 = 0.f, fR0 = 0.f, fR1 = 0.f;
  if (bx > 0) { fm2 = SM(bid - 1, 6); fm1 = SM(bid - 1, 7); }
  if (bx < 5) { fR0 = SM(bid + 1, 0); fR1 = SM(bid + 1, 1); }
  const float f0 = SM(bid, 0), f1 = SM(bid, 1), f2 = SM(bid, 2), f3 = SM(bid, 3);
  const float f124 = SM(bid, 4), f125 = SM(bid, 5), f126 = SM(bid, 6), f127 = SM(bid, 7);
  #undef SM
  #define C1(a, b, c) fmaxf(fmaf(w10, (a), fmaf(w11, (b), fmaf(w12, (c), c1b))), 0.0f)
  const float tm1  = (bx > 0) ? C1(fm2, fm1, f0) : 0.0f;   // tmp(-1)=0 at edge
  const float t0   = C1(fm1, f0, f1);
  const float t1   = C1(f0, f1, f2);
  const float t2   = C1(f1, f2, f3);
  const float t125 = C1(f124, f125, f126);
  const float t126 = C1(f125, f126, f127);
  const float t127 = C1(f126, f127, fR0);
  const float t128 = (bx < 5) ? C1(f127, fR0, fR1) : 0.0f;  // tmp(768)=0 at edge
  #undef C1
  const size_t go = (size_t)(by * 256 + r) * Dn + bx * 128;
  out[go + 0]   = fmaf(w20, tm1,  fmaf(w21, t0,   fmaf(w22, t1,   c2b)));
  out[go + 1]   = fmaf(w20, t0,   fmaf(w21, t1,   fmaf(w22, t2,   c2b)));
  out[go + 126] = fmaf(w20, t125, fmaf(w21, t126, fmaf(w22, t127, c2b)));
  out[go + 127] = fmaf(w20, t126, fmaf(w21, t127, fmaf(w22, t128, c2b)));
}

extern "C" void kernel_launch(void* const* d_in, const int* in_sizes, int n_in,
                              void* d_out, int out_size, void* d_ws, size_t ws_size,
                              hipStream_t stream) {
  const float* text = (const float*)d_in[0];
  const float* vf   = (const float*)d_in[1];
  const float* W1   = (const float*)d_in[2];
  const float* b1   = (const float*)d_in[3];
  const float* W2   = (const float*)d_in[4];
  const float* b2   = (const float*)d_in[5];
  const float* cw1  = (const float*)d_in[6];
  const float* cb1  = (const float*)d_in[7];
  const float* cw2  = (const float*)d_in[8];
  const float* cb2  = (const float*)d_in[9];
  float* out = (float*)d_out;

  u8*  X8   = (u8*)d_ws;                                   // [320 panels] tiled i8 v3
  u8*  Wt8  = X8 + (size_t)Mn * Dn;                        // [6 panels] tiled i8 v3
  u16* seam = (u16*)(Wt8 + (size_t)Nn * Dn);               // [1920][8][256] bf16
  float* invs = (float*)(seam + (size_t)GRID * 8 * 256);   // [81920] per-row 1/s
  unsigned* wm = (unsigned*)(invs + Mn);                   // global max|W|

  zero_k<<<1, 1, 0, stream>>>(wm);
  wmax_k<<<64, 256, 0, stream>>>(W1, W2, wm);
  softmax_k<<<Mn / 32, 512, 0, stream>>>(vf, X8, invs);
  build_wt_k<<<(Dn * (Dn / 4) + 255) / 256, 256, 0, stream>>>(W1, W2, Wt8, wm);
  gemm_fuse_k<<<GRID, 512, 0, stream>>>(X8, Wt8, b1, b2, text, out, seam,
                                        invs, wm, cw1, cb1, cw2, cb2);
  seam_k<<<GRID, 256, 0, stream>>>(seam, out, cw1, cb1, cw2, cb2);
}